// Round 15
// baseline (483.614 us; speedup 1.0000x reference)
//
#include <hip/hip_runtime.h>

#define R_ 3
#define T_ 3
#define N_ 50000
#define OPS_ 24
#define E_ 400000
#define B_ 32
#define MAXDEG_ 8
#define QD_ 128
#define ED_ 128
#define H_ 128
#define G4_ (4*H_)   /* 512 */
#define HPAD 168     /* padded LDS h-row (bf16): 128 h + 25 one-hot + pad, 336 B */
#define PSLOTS 64    /* partial row-sum slots */
#define RB_ 96       /* 3 rounds x 32 batch */

/* front fat-kernel block ranges (512-thread blocks) */
#define WB_ ((2*32*5*64*8 + 511) / 512)        /* 320  wbuild */
#define CB_ ((E_ + 511) / 512)                 /* 782  csr_count */
#define BF_ ((E_ + 511) / 512)                 /* 782  bfs1 (1-hop mark) */
#define ZU_ 586                                /* u2 zero: 4.8M floats / 8192 */
#define ZM_ ((N_ + 511) / 512)                 /* 98   mask-int zero */
#define ZS_ 12                                 /* sumsP zero: 6144 / 512 */
#define EB_ 16                                 /* etile build: 8192 / 512 */

/* elstm mega-grid layout: [qattn 96][elstm 1563][scan 1][bfs2 880]
   (r11-r14 measured: qattn at head ~5-10us slot pinning; at tail +27us
   critical-path anchor; cheap scan/bfs2 riders free in the drain.) */
#define QB_ (R_ * B_)                          /* 96  qattn riders (first) */
#define SCANBLK_ ((N_ + 31) / 32)              /* 1563 elstm blocks */
#define BF2E_ ((E_ + 511) / 512)               /* 782 bfs2 edge riders */
#define BF2N_ ((N_ + 511) / 512)               /* 98  bfs2 node riders */

typedef unsigned short u16;
typedef unsigned char u8;
typedef __attribute__((ext_vector_type(8))) short bf16x8;     // 8 bf16 = 4 VGPRs
typedef __attribute__((ext_vector_type(8))) _Float16 f16x8;   // 8 f16  = 4 VGPRs
typedef __attribute__((ext_vector_type(4))) float f32x4;

#define BF16_ONE ((short)0x3F80)
#define LOG2E_  1.44269504f
#define LOG2E2_ 2.88539008f

__device__ __forceinline__ short f2bf(float f){
  union { float f; unsigned u; } v; v.f = f;
  unsigned r = v.u + 0x7fffu + ((v.u >> 16) & 1u);
  return (short)(r >> 16);
}
__device__ __forceinline__ float bf2f(u16 u){
  union { unsigned u; float f; } v; v.u = ((unsigned)u) << 16; return v.f;
}
__device__ __forceinline__ float frcp(float x){ return __builtin_amdgcn_rcpf(x); }
__device__ __forceinline__ float fsig(float x){ return frcp(1.0f + __expf(-x)); }
__device__ __forceinline__ float ftanh(float x){
  return __builtin_fmaf(2.0f, fsig(2.0f * x), -1.0f);
}
__device__ __forceinline__ float fexp2(float x){
#if __has_builtin(__builtin_amdgcn_exp2f)
  return __builtin_amdgcn_exp2f(x);
#else
  return __expf(x * 0.6931471806f);
#endif
}

// ------- query BiLSTM + attention: 512-thread body, dirs run concurrently -------
__device__ void qattn_body(int bid, const int* __restrict__ queries, const float* __restrict__ qemb,
    const float* __restrict__ qWih, const float* __restrict__ qWhh,
    const float* __restrict__ qbih, const float* __restrict__ qbhh,
    const float* __restrict__ qlinW, const float* __restrict__ qlinb,
    float* __restrict__ query_attn /* R,T,B,25 */)
{
  int r = bid / B_;
  int b = bid % B_;
  int tid = threadIdx.x;   // 512
  int d   = tid >> 8;      // direction
  int t2  = tid & 255;
  __shared__ float x[QD_];
  __shared__ float gx[2][G4_];
  __shared__ float h[2][H_], c[2][H_];
  __shared__ float gtmp[2][G4_];
  __shared__ float hh[2][T_][H_];
  __shared__ float lg[OPS_ + 1];

  int q = queries[b];
  if (tid < QD_) x[tid] = qemb[q * QD_ + tid];
  __syncthreads();

  const float* Wih = qWih + (size_t)(r * 2 + d) * G4_ * QD_;
  const float* Whh = qWhh + (size_t)(r * 2 + d) * G4_ * H_;
  const float* bih = qbih + (r * 2 + d) * G4_;
  const float* bhh = qbhh + (r * 2 + d) * G4_;
  for (int j = t2; j < G4_; j += 256){
    const float4* wr = (const float4*)(Wih + (size_t)j * QD_);
    float s = bih[j] + bhh[j];
    for (int k = 0; k < QD_ / 4; ++k){
      float4 wv = wr[k];
      s += wv.x * x[4*k] + wv.y * x[4*k+1] + wv.z * x[4*k+2] + wv.w * x[4*k+3];
    }
    gx[d][j] = s;
  }
  if (t2 < H_){ h[d][t2] = 0.f; c[d][t2] = 0.f; }
  __syncthreads();
  for (int t = 0; t < T_; ++t){
    for (int j = t2; j < G4_; j += 256){
      const float4* wr = (const float4*)(Whh + (size_t)j * H_);
      float s = 0.f;
      for (int k = 0; k < H_ / 4; ++k){
        float4 wv = wr[k];
        s += wv.x * h[d][4*k] + wv.y * h[d][4*k+1] + wv.z * h[d][4*k+2] + wv.w * h[d][4*k+3];
      }
      gtmp[d][j] = gx[d][j] + s;
    }
    __syncthreads();
    if (t2 < H_){
      float gi = gtmp[d][t2], gf = gtmp[d][t2 + H_], gg = gtmp[d][t2 + 2*H_], go = gtmp[d][t2 + 3*H_];
      float cn = fsig(gf) * c[d][t2] + fsig(gi) * ftanh(gg);
      float hn = fsig(go) * ftanh(cn);
      c[d][t2] = cn; h[d][t2] = hn;
      hh[d][t][t2] = hn;
    }
    __syncthreads();
  }

  for (int t = 0; t < T_; ++t){
    if (tid < OPS_ + 1){
      const float* wr = qlinW + tid * (2 * H_);
      float s = qlinb[tid];
      for (int k = 0; k < H_; ++k) s += wr[k] * hh[0][t][k];
      for (int k = 0; k < H_; ++k) s += wr[H_ + k] * hh[1][T_ - 1 - t][k];
      lg[tid] = s;
    }
    __syncthreads();
    if (tid == 0){
      float m = -1e30f;
      for (int o = 0; o < OPS_ + 1; ++o) m = fmaxf(m, lg[o]);
      float sum = 0.f;
      for (int o = 0; o < OPS_ + 1; ++o){ float e = __expf(lg[o] - m); lg[o] = e; sum += e; }
      float inv = frcp(sum);
      for (int o = 0; o < OPS_ + 1; ++o) lg[o] *= inv;
    }
    __syncthreads();
    if (tid < OPS_ + 1) query_attn[((size_t)(r * T_ + t) * B_ + b) * (OPS_ + 1) + tid] = lg[tid];
    __syncthreads();
  }
}

// ---- build B-operand buffers in MFMA-fragment order (eproj folded in) ----
__device__ void wbuild_body(int bid, const float* __restrict__ eWhh,
                            const float* __restrict__ eemb, const float* __restrict__ eWih,
                            const float* __restrict__ ebih, const float* __restrict__ ebhh,
                            u16* __restrict__ wtile, u16* __restrict__ wonehot)
{
  int idx = bid * 512 + threadIdx.x;    // 2*32*5*64*8 = 163840
  if (idx >= 2 * 32 * 5 * 64 * 8) return;
  int jj = idx & 7;
  int lane = (idx >> 3) & 63;
  int kc = (idx >> 9) % 5;
  int gtile = (idx / (8 * 64 * 5)) & 31;
  int dir = idx / (8 * 64 * 5 * 32);
  int row = lane >> 4, col = lane & 15;
  int j = gtile * 16 + col;
  float sc = ((gtile >> 3) == 2) ? LOG2E2_ : LOG2E_;   // gate g rows get 2*log2e
  if (kc < 4){
    int k = kc * 32 + row * 8 + jj;
    float v = eWhh[((size_t)dir * G4_ + j) * H_ + k] * sc;
    wtile[((((size_t)dir * 32 + gtile) * 4 + kc) * 64 + lane) * 8 + jj] = (u16)f2bf(v);
  } else {
    int vdeg = row * 8 + jj;   // 0..31
    float v = 0.f;
    if (vdeg <= OPS_){
      const float4* wr = (const float4*)(eWih + (size_t)(dir * G4_ + j) * ED_);
      const float4* er = (const float4*)(eemb + (size_t)vdeg * ED_);
      float s = ebih[dir * G4_ + j] + ebhh[dir * G4_ + j];
      for (int k = 0; k < ED_ / 4; ++k){
        float4 wv = wr[k], ev = er[k];
        s += wv.x * ev.x + wv.y * ev.y + wv.z * ev.z + wv.w * ev.w;
      }
      v = s * sc;
    }
    wonehot[(((size_t)dir * 32 + gtile) * 64 + lane) * 8 + jj] = (u16)f2bf(v);
  }
}

__device__ void csr_count_body(int bid, const int* __restrict__ theads,
                               const int* __restrict__ ttails, int* __restrict__ counts)
{
  int e = bid * 512 + threadIdx.x;
  if (e < E_){
    atomicAdd(&counts[ttails[e]], 1);
    atomicAdd(&counts[theads[e]], 1);
  }
}

// ---- bfs1: mark 1-hop neighborhood of heads (both edge roles) + heads selves.
__device__ void bfs1_body(int bid, const int* __restrict__ heads,
                          const int* __restrict__ theads, const int* __restrict__ ttails,
                          u8* __restrict__ hs1)
{
  if (bid == 0 && threadIdx.x < B_) hs1[heads[threadIdx.x]] = 1;
  int e = bid * 512 + threadIdx.x;
  if (e < E_){
    int a = theads[e], t = ttails[e];
    #pragma unroll 8
    for (int i = 0; i < B_; ++i){
      int hd = heads[i];             // uniform -> scalar loads
      if (a == hd) hs1[t] = 1;
      if (t == hd) hs1[a] = 1;
    }
  }
}

// ---- front fat-kernel: wbuild | csr_count | bfs1 | zero(u2,mask,sumsP) | etile
__global__ __launch_bounds__(512) void front_kernel(
    const float* eWhh, const float* eemb, const float* eWih,
    const float* ebih, const float* ebhh, u16* wtile, u16* wonehot,
    const int* theads, const int* ttails, int* counts,
    const int* heads, u8* hs1,
    float* u2, int* maski, float* sumsP,
    const float* elinW, u16* etile)
{
  int bid = blockIdx.x;
  int tid = threadIdx.x;
  if (bid < WB_){
    wbuild_body(bid, eWhh, eemb, eWih, ebih, ebhh, wtile, wonehot);
  } else if (bid < WB_ + CB_){
    csr_count_body(bid - WB_, theads, ttails, counts);
  } else if (bid < WB_ + CB_ + BF_){
    bfs1_body(bid - WB_ - CB_, heads, theads, ttails, hs1);
  } else if (bid < WB_ + CB_ + BF_ + ZU_){
    int zb = bid - WB_ - CB_ - BF_;
    float4 z = {0.f, 0.f, 0.f, 0.f};
    size_t base = (size_t)zb * 8192 + tid * 4;
    #pragma unroll
    for (int k = 0; k < 4; ++k){
      size_t idx = base + (size_t)k * 2048;
      if (idx < (size_t)N_ * RB_) *(float4*)&u2[idx] = z;
    }
  } else if (bid < WB_ + CB_ + BF_ + ZU_ + ZM_){
    int mi = (bid - WB_ - CB_ - BF_ - ZU_) * 512 + tid;
    if (mi < N_) maski[mi] = 0;
  } else if (bid < WB_ + CB_ + BF_ + ZU_ + ZM_ + ZS_){
    int si = (bid - WB_ - CB_ - BF_ - ZU_ - ZM_) * 512 + tid;
    if (si < PSLOTS * RB_) sumsP[si] = 0.f;
  } else {
    // elinW -> f16 MFMA B-frags: [2 op-tiles][8 ksteps][64 lanes][8] (16 KB)
    int idx = (bid - (WB_ + CB_ + BF_ + ZU_ + ZM_ + ZS_)) * 512 + tid;   // 0..8191
    if (idx < 8192){
      int jj = idx & 7;
      int lane = (idx >> 3) & 63;
      int ks = (idx >> 9) & 7;
      int ot = idx >> 12;
      int op = ot * 16 + (lane & 15);
      int k  = ks * 32 + (lane >> 4) * 8 + jj;
      float v = (op < OPS_) ? elinW[(size_t)op * (2 * H_) + k] : 0.f;
      _Float16 hv = (_Float16)v;
      etile[idx] = *(const u16*)&hv;
    }
  }
}

// ---- bfs2 body: 2-hop closure + COMPACT ROW NUMBERING. mask[n]=1 claimed via
// CAS exactly once; the claimer assigns cidx[n] from a shared counter (rides in
// counts[N_], unused by count/scan). u2 rows are indexed by cidx -> the hot
// working set of t01/gather3 shrinks 19.2MB -> ~3.5MB (fits one XCD's 4MB L2).
// cidx consumed only by LATER launches -> no intra-kernel ordering needed.
__device__ void bfs2_body(int bid, const int* __restrict__ theads,
                          const int* __restrict__ ttails,
                          const u8* __restrict__ hs1, int* __restrict__ mask,
                          int* __restrict__ cidx, int* __restrict__ cnt)
{
  if (bid < BF2E_){
    int e = bid * 512 + threadIdx.x;
    if (e < E_){
      int a = theads[e], t = ttails[e];
      if (hs1[a] && atomicCAS(&mask[t], 0, 1) == 0) cidx[t] = atomicAdd(cnt, 1);
      if (hs1[t] && atomicCAS(&mask[a], 0, 1) == 0) cidx[a] = atomicAdd(cnt, 1);
    }
  } else {
    int n = (bid - BF2E_) * 512 + threadIdx.x;
    if (n < N_ && hs1[n] && atomicCAS(&mask[n], 0, 1) == 0) cidx[n] = atomicAdd(cnt, 1);
  }
}

// ---- coalesced tile scan (512 threads, tail rider of the elstm grid).
__device__ void scan_body(const int* __restrict__ counts, int* __restrict__ rowptr,
                          int* __restrict__ cursor, int* __restrict__ cursor2)
{
  __shared__ int wsum[8];
  int t = threadIdx.x;
  int lane = t & 63, wv = t >> 6;
  int carry = 0;   // live only in thread 0
  for (int base = 0; base < N_; base += 2048){
    int idx = base + t * 4;
    int c0 = 0, c1 = 0, c2 = 0, c3 = 0;
    if (idx + 3 < N_){
      int4 c = *(const int4*)&counts[idx];
      c0 = c.x; c1 = c.y; c2 = c.z; c3 = c.w;
    } else {
      if (idx     < N_) c0 = counts[idx];
      if (idx + 1 < N_) c1 = counts[idx + 1];
      if (idx + 2 < N_) c2 = counts[idx + 2];
      if (idx + 3 < N_) c3 = counts[idx + 3];
    }
    int s = c0 + c1 + c2 + c3;
    int sc = s;                          // inclusive wave scan
    #pragma unroll
    for (int off = 1; off < 64; off <<= 1){
      int v = __shfl_up(sc, off);
      if (lane >= off) sc += v;
    }
    if (lane == 63) wsum[wv] = sc;
    __syncthreads();
    if (t == 0){
      int acc = carry;
      #pragma unroll
      for (int w = 0; w < 8; ++w){ int v = wsum[w]; wsum[w] = acc; acc += v; }
      carry = acc;
    }
    __syncthreads();
    int excl = wsum[wv] + (sc - s);
    int r0 = excl, r1 = r0 + c0, r2 = r1 + c1, r3 = r2 + c2;
    if (idx + 3 < N_){
      int4 rv; rv.x = r0; rv.y = r1; rv.z = r2; rv.w = r3;
      *(int4*)&rowptr[idx]  = rv;
      *(int4*)&cursor[idx]  = rv;
      *(int4*)&cursor2[idx] = rv;
    } else {
      if (idx     < N_){ rowptr[idx]   = r0; cursor[idx]   = r0; cursor2[idx]   = r0; }
      if (idx + 1 < N_){ rowptr[idx+1] = r1; cursor[idx+1] = r1; cursor2[idx+1] = r1; }
      if (idx + 2 < N_){ rowptr[idx+2] = r2; cursor[idx+2] = r2; cursor2[idx+2] = r2; }
      if (idx + 3 < N_){ rowptr[idx+3] = r3; cursor[idx+3] = r3; cursor2[idx+3] = r3; }
    }
  }
  if (t == 0) rowptr[N_] = carry;
}

// ------ elstm MEGA-kernel, grid = [qattn 96][elstm 1563][scan+bfs2 881] (r12 order).
__global__ __launch_bounds__(512, 4) void elstm_kernel(
    const int* __restrict__ degs,
    const u16* __restrict__ wtile, const u16* __restrict__ wonehot,
    const u16* __restrict__ etile, const float* __restrict__ elinb,
    float* __restrict__ attn /* N,24 */,
    int* __restrict__ counts, int* __restrict__ rowptr,
    int* __restrict__ cursor, int* __restrict__ cursor2,
    const int* __restrict__ theads, const int* __restrict__ ttails,
    const u8* __restrict__ hs1, int* __restrict__ mask, int* __restrict__ cidx,
    const int* __restrict__ queries, const float* __restrict__ qemb,
    const float* __restrict__ qWih, const float* __restrict__ qWhh,
    const float* __restrict__ qbih, const float* __restrict__ qbhh,
    const float* __restrict__ qlinW, const float* __restrict__ qlinb,
    float* __restrict__ query_attn)
{
  int bid = blockIdx.x;
  if (bid < QB_){
    qattn_body(bid, queries, qemb, qWih, qWhh, qbih, qbhh, qlinW, qlinb, query_attn);
    return;
  }
  int eb = bid - QB_;
  if (eb >= SCANBLK_){
    int rid = eb - SCANBLK_;
    if (rid == 0) scan_body(counts, rowptr, cursor, cursor2);
    else          bfs2_body(rid - 1, theads, ttails, hs1, mask, cidx, &counts[N_]);
    return;
  }

  int tid = threadIdx.x;
  int lane = tid & 63;
  int w = tid >> 6;          // wave 0..7
  int wu = __builtin_amdgcn_readfirstlane(w);   // provably wave-uniform
  int row = lane >> 4, col = lane & 15;
  int ebase = eb * 32;

  __shared__ __align__(16) short hl[2][32 * HPAD];   // 2 x 10.5 KB ping-pong
  __shared__ __align__(16) short hfin[32 * 136];     // dir0 final h (8.5 KB)
  __shared__ float lgs[32][33];                      // epilogue logits (4.2 KB)

  int eg0 = ebase + tid; if (eg0 >= N_) eg0 = N_ - 1;   // valid for tid<32 use

  for (int i = tid; i < 2 * 32 * HPAD; i += 512) ((short*)hl)[i] = 0;
  __syncthreads();
  if (tid < 32) hl[0][tid * HPAD + H_ + degs[(size_t)eg0 * MAXDEG_ + 0]] = BF16_ONE;
  __syncthreads();

  int swzr = (col >> 2) & 3;   // read-side swizzle for entities col and 16+col

  for (int dir = 0; dir < 2; ++dir){
    const u16* Wt  = wtile   + (size_t)dir * 32 * 4 * 64 * 8;
    const u16* Woh = wonehot + (size_t)dir * 32 * 64 * 8;
    const u16* W0 = Wt + (size_t)((0 * 8 + wu) * 4 * 64) * 8;
    const u16* W1 = Wt + (size_t)((1 * 8 + wu) * 4 * 64) * 8;
    const u16* W2 = Wt + (size_t)((2 * 8 + wu) * 4 * 64) * 8;
    const u16* W3 = Wt + (size_t)((3 * 8 + wu) * 4 * 64) * 8;
    const u16* O0 = Woh + (size_t)((0 * 8 + wu) * 64) * 8;
    const u16* O1 = Woh + (size_t)((1 * 8 + wu) * 64) * 8;
    const u16* O2 = Woh + (size_t)((2 * 8 + wu) * 64) * 8;
    const u16* O3 = Woh + (size_t)((3 * 8 + wu) * 64) * 8;
    float cst[8];
    #pragma unroll
    for (int i = 0; i < 8; ++i) cst[i] = 0.f;

    for (int t = 0; t < MAXDEG_; ++t){
      const short* hb = hl[t & 1];          // holds h_t (+ one-hot for step t)
      short*       hw = hl[(t + 1) & 1];    // receives h_{t+1}
      f32x4 acc[8];
      #pragma unroll
      for (int i = 0; i < 8; ++i) acc[i] = (f32x4){0.f, 0.f, 0.f, 0.f};

      #pragma unroll 2
      for (int kc = 0; kc < 4; ++kc){
        bf16x8 af0 = *(const bf16x8*)&hb[(col) * HPAD + kc * 32 + (row ^ swzr) * 8];
        bf16x8 af1 = *(const bf16x8*)&hb[(16 + col) * HPAD + kc * 32 + (row ^ swzr) * 8];
        int lo = (kc * 64 + lane) * 8;
        bf16x8 b0 = *(const bf16x8*)(W0 + lo);
        bf16x8 b1 = *(const bf16x8*)(W1 + lo);
        bf16x8 b2 = *(const bf16x8*)(W2 + lo);
        bf16x8 b3 = *(const bf16x8*)(W3 + lo);
        acc[0] = __builtin_amdgcn_mfma_f32_16x16x32_bf16(af0, b0, acc[0], 0, 0, 0);
        acc[1] = __builtin_amdgcn_mfma_f32_16x16x32_bf16(af1, b0, acc[1], 0, 0, 0);
        acc[2] = __builtin_amdgcn_mfma_f32_16x16x32_bf16(af0, b1, acc[2], 0, 0, 0);
        acc[3] = __builtin_amdgcn_mfma_f32_16x16x32_bf16(af1, b1, acc[3], 0, 0, 0);
        acc[4] = __builtin_amdgcn_mfma_f32_16x16x32_bf16(af0, b2, acc[4], 0, 0, 0);
        acc[5] = __builtin_amdgcn_mfma_f32_16x16x32_bf16(af1, b2, acc[5], 0, 0, 0);
        acc[6] = __builtin_amdgcn_mfma_f32_16x16x32_bf16(af0, b3, acc[6], 0, 0, 0);
        acc[7] = __builtin_amdgcn_mfma_f32_16x16x32_bf16(af1, b3, acc[7], 0, 0, 0);
      }
      {
        bf16x8 af0 = *(const bf16x8*)&hb[(col) * HPAD + H_ + row * 8];
        bf16x8 af1 = *(const bf16x8*)&hb[(16 + col) * HPAD + H_ + row * 8];
        int lo = lane * 8;
        bf16x8 b0 = *(const bf16x8*)(O0 + lo);
        bf16x8 b1 = *(const bf16x8*)(O1 + lo);
        bf16x8 b2 = *(const bf16x8*)(O2 + lo);
        bf16x8 b3 = *(const bf16x8*)(O3 + lo);
        acc[0] = __builtin_amdgcn_mfma_f32_16x16x32_bf16(af0, b0, acc[0], 0, 0, 0);
        acc[1] = __builtin_amdgcn_mfma_f32_16x16x32_bf16(af1, b0, acc[1], 0, 0, 0);
        acc[2] = __builtin_amdgcn_mfma_f32_16x16x32_bf16(af0, b1, acc[2], 0, 0, 0);
        acc[3] = __builtin_amdgcn_mfma_f32_16x16x32_bf16(af1, b1, acc[3], 0, 0, 0);
        acc[4] = __builtin_amdgcn_mfma_f32_16x16x32_bf16(af0, b2, acc[4], 0, 0, 0);
        acc[5] = __builtin_amdgcn_mfma_f32_16x16x32_bf16(af1, b2, acc[5], 0, 0, 0);
        acc[6] = __builtin_amdgcn_mfma_f32_16x16x32_bf16(af0, b3, acc[6], 0, 0, 0);
        acc[7] = __builtin_amdgcn_mfma_f32_16x16x32_bf16(af1, b3, acc[7], 0, 0, 0);
      }

      #pragma unroll
      for (int mt = 0; mt < 2; ++mt){
        #pragma unroll
        for (int reg = 0; reg < 4; ++reg){
          int e = mt * 16 + row * 4 + reg;
          int jsw = (((wu * 2 + (col >> 3)) ^ row) * 8) + (col & 7);
          float Gi = acc[0 + mt][reg];
          float Gf = acc[2 + mt][reg];
          float Gg = acc[4 + mt][reg];
          float Go = acc[6 + mt][reg];
          int ci = mt * 4 + reg;
          float ea = fexp2(-Gi);
          float ef = fexp2(-Gf);
          float eb2 = fexp2(-Gg);
          float eo = fexp2(-Go);
          float t1 = 1.f + ef, t2 = 1.f + ea, t3 = 1.f + eb2;
          float p = t2 * t3;
          float num = __builtin_fmaf(cst[ci], p, (1.f - eb2) * t1);
          float cn = num * frcp(t1 * p);
          float ed = fexp2(cn * (-LOG2E2_));
          float hn = (1.f - ed) * frcp((1.f + eo) * (1.f + ed));
          cst[ci] = cn;
          hw[e * HPAD + jsw] = f2bf(hn);
        }
      }
      if (tid < 32){
        const int* dr = degs + (size_t)eg0 * MAXDEG_;
        if (t >= 1)
          hw[tid * HPAD + H_ + dr[dir ? (MAXDEG_ - t) : (t - 1)]] = 0;
        if (t < MAXDEG_ - 1)
          hw[tid * HPAD + H_ + dr[dir ? (MAXDEG_ - 2 - t) : (t + 1)]] = BF16_ONE;
      }
      __syncthreads();
    }

    if (dir == 0){
      for (int i = tid; i < 32 * 16; i += 512){
        int e = i >> 4, c = i & 15;
        int sz = (e >> 2) & 3;
        *(bf16x8*)&hfin[e * 136 + c * 8] =
            *(const bf16x8*)&hl[0][e * HPAD + ((c ^ sz) * 8)];
      }
      __syncthreads();
      for (int i = tid; i < 2 * 32 * HPAD; i += 512) ((short*)hl)[i] = 0;
      __syncthreads();
      if (tid < 32) hl[0][tid * HPAD + H_ + degs[(size_t)eg0 * MAXDEG_ + (MAXDEG_ - 1)]] = BF16_ONE;
      __syncthreads();
    }
  }

  // fused entity-attention epilogue
  if (wu < 4){
    int mt = wu >> 1, ot = wu & 1;
    int e2 = mt * 16 + col;
    f32x4 accL = (f32x4){0.f, 0.f, 0.f, 0.f};
    #pragma unroll
    for (int ks = 0; ks < 8; ++ks){
      bf16x8 ra;
      if (ks < 4) ra = *(const bf16x8*)&hfin[e2 * 136 + ks * 32 + row * 8];
      else        ra = *(const bf16x8*)&hl[0][e2 * HPAD + (ks - 4) * 32 + (row ^ swzr) * 8];
      f16x8 af;
      #pragma unroll
      for (int jj = 0; jj < 8; ++jj) af[jj] = (_Float16)bf2f((u16)ra[jj]);
      f16x8 bfr = *(const f16x8*)(etile + (((size_t)(ot * 8 + ks)) * 64 + lane) * 8);
      accL = __builtin_amdgcn_mfma_f32_16x16x32_f16(af, bfr, accL, 0, 0, 0);
    }
    #pragma unroll
    for (int reg = 0; reg < 4; ++reg){
      int ent = mt * 16 + (lane >> 4) * 4 + reg;
      int op  = ot * 16 + (lane & 15);
      float bb = (op < OPS_) ? elinb[op] : 0.f;
      lgs[ent][op] = accL[reg] + bb;
    }
  }
  __syncthreads();
  if (tid < 32){
    int n = ebase + tid;
    if (n < N_){
      float m = -1e30f;
      #pragma unroll
      for (int o = 0; o < OPS_; ++o) m = fmaxf(m, lgs[tid][o]);
      float s = 0.f;
      #pragma unroll
      for (int o = 0; o < OPS_; ++o) s += __expf(lgs[tid][o] - m);
      float inv = frcp(s);
      #pragma unroll
      for (int o = 0; o < OPS_; ++o)
        attn[(size_t)n * OPS_ + o] = __expf(lgs[tid][o] - m) * inv;
    }
  }
}

// ---- compact CSR fill (mask now int) ----
__global__ void csr_fill_kernel(const int* __restrict__ rels, const int* __restrict__ theads,
                                const int* __restrict__ ttails, const float* __restrict__ attn,
                                const int* __restrict__ mask, const u8* __restrict__ hs1,
                                int* __restrict__ cursor, int* __restrict__ cursor2,
                                uint2* __restrict__ ents, uint2* __restrict__ ents2)
{
  int e = blockIdx.x * 256 + threadIdx.x;
  if (e < E_){
    int hh = theads[e], tt = ttails[e];
    int mh = mask[hh], mt = mask[tt];
    if (!(mh | mt)) return;
    int rel = rels[e];
    unsigned wb = __float_as_uint(attn[(size_t)hh * OPS_ + rel]);
    if (mh){                         // fwd: src hh -> row tt
      uint2 v1; v1.x = (unsigned)hh | ((unsigned)rel << 16); v1.y = wb;
      ents[atomicAdd(&cursor[tt], 1)] = v1;
    }
    if (mt){                         // rev: src tt -> row hh
      uint2 v2; v2.x = (unsigned)tt | ((unsigned)(rel + OPS_/2) << 16); v2.y = wb;
      ents[atomicAdd(&cursor[hh], 1)] = v2;
    }
    if (hs1[hh]){                    // out-edge of hh
      uint2 w1; w1.x = (unsigned)tt | ((unsigned)rel << 16); w1.y = wb;
      ents2[atomicAdd(&cursor2[hh], 1)] = w1;
    }
    if (hs1[tt]){                    // out-edge of tt (reverse op)
      uint2 w2; w2.x = (unsigned)hh | ((unsigned)(rel + OPS_/2) << 16); w2.y = wb;
      ents2[atomicAdd(&cursor2[tt], 1)] = w2;
    }
  }
}

// ---- fused sparse t=0 + t=1 -> COMPACT u2 rows (cidx indirection) ----
__global__ void t01_kernel(const int* __restrict__ heads, const float* __restrict__ query_attn,
                           const int* __restrict__ rowptr, const int* __restrict__ cend2,
                           const uint2* __restrict__ ents2, const int* __restrict__ cidx,
                           float* __restrict__ u2c)
{
  __shared__ float qa0[OPS_ + 1], qa1[OPS_ + 1];
  int blk = blockIdx.x;   // 0..95
  int r = blk >> 5, b = blk & 31;
  int rb = r * 32 + b;
  int tid = threadIdx.x;  // 64
  if (tid < OPS_ + 1){
    qa0[tid] = query_attn[((size_t)(r * T_ + 0) * B_ + b) * (OPS_ + 1) + tid];
    qa1[tid] = query_attn[((size_t)(r * T_ + 1) * B_ + b) * (OPS_ + 1) + tid];
  }
  __syncthreads();
  int hd = heads[b];
  int beg = rowptr[hd], end = cend2[hd];
  float q024 = qa0[OPS_], q124 = qa1[OPS_];
  if (tid == 0) atomicAdd(&u2c[(size_t)cidx[hd] * RB_ + rb], q124 * q024);
  for (int i = beg + tid; i < end; i += 64){
    uint2 e1 = ents2[i];
    int s  = (int)(e1.x & 0xFFFFu);
    int r1 = (int)(e1.x >> 16);
    float w1 = __uint_as_float(e1.y);
    atomicAdd(&u2c[(size_t)cidx[s] * RB_ + rb], w1 * (q124 * qa0[r1] + qa1[r1] * q024));
    float v1 = qa0[r1] * w1;      // this path's share of u1[s]
    int b2 = rowptr[s], e2e = cend2[s];
    for (int jj = b2; jj < e2e; ++jj){
      uint2 e2 = ents2[jj];
      int d2 = (int)(e2.x & 0xFFFFu);
      int r2 = (int)(e2.x >> 16);
      atomicAdd(&u2c[(size_t)cidx[d2] * RB_ + rb], qa1[r2] * __uint_as_float(e2.y) * v1);
    }
  }
}

// ---- dense gather (t=2): half-wave per node, COMPACT u2 source rows (cidx).
// Working set ~3.5MB fits one XCD's L2 -> edge row reads hit L2 not L3/HBM.
__global__ __launch_bounds__(256) void gather3_kernel(
    const float* __restrict__ ucur_c, float* __restrict__ unxt,
    const float* __restrict__ query_attn, int t,
    const int* __restrict__ rowptr, const int* __restrict__ cend,
    const uint2* __restrict__ ents, const int* __restrict__ mask,
    const int* __restrict__ cidx,
    float* __restrict__ partial /* PSLOTS x 96 */)
{
  __shared__ float qas[3 * B_ * (OPS_ + 1)];  // [r][b][o]
  __shared__ float red[RB_];
  int tid = threadIdx.x;
  for (int i = tid; i < 3 * B_ * (OPS_ + 1); i += 256){
    int r = i / (B_ * (OPS_ + 1));
    int rem = i - r * (B_ * (OPS_ + 1));
    qas[i] = query_attn[(size_t)(r * T_ + t) * B_ * (OPS_ + 1) + rem];
  }
  if (tid < RB_) red[tid] = 0.f;
  __syncthreads();
  int b   = tid & 31;
  int hw2 = tid >> 5;                  // half-wave 0..7, one node each
  const float* q0 = &qas[0 * 800 + b * (OPS_ + 1)];
  const float* q1 = &qas[1 * 800 + b * (OPS_ + 1)];
  const float* q2 = &qas[2 * 800 + b * (OPS_ + 1)];
  float s0a = 0.f, s1a = 0.f, s2a = 0.f;
  for (int n = blockIdx.x * 8 + hw2; n < N_; n += gridDim.x * 8){
    int beg = rowptr[n], end = cend[n];
    int mk = mask[n];
    if (end == beg && !mk) continue;   // dead row: fintrans zero-fills
    size_t nb = (size_t)n * RB_;
    float a0 = 0.f, a1 = 0.f, a2 = 0.f;
    if (mk){
      size_t cb = (size_t)cidx[n] * RB_;
      a0 = ucur_c[cb + b]      * q0[OPS_];
      a1 = ucur_c[cb + 32 + b] * q1[OPS_];
      a2 = ucur_c[cb + 64 + b] * q2[OPS_];
    }
    #pragma unroll 2
    for (int i = beg; i < end; ++i){
      uint2 e0 = ents[i];              // uniform across the half -> broadcast
      size_t s0 = (size_t)cidx[e0.x & 0xFFFFu] * RB_;   // src masked by construction
      int r0 = (int)(e0.x >> 16);
      float w0 = __uint_as_float(e0.y);
      a0 += q0[r0] * w0 * ucur_c[s0 + b];
      a1 += q1[r0] * w0 * ucur_c[s0 + 32 + b];
      a2 += q2[r0] * w0 * ucur_c[s0 + 64 + b];
    }
    unxt[nb + b]      = a0;
    unxt[nb + 32 + b] = a1;
    unxt[nb + 64 + b] = a2;
    s0a += a0; s1a += a1; s2a += a2;
  }
  atomicAdd(&red[b], s0a);
  atomicAdd(&red[32 + b], s1a);
  atomicAdd(&red[64 + b], s2a);
  __syncthreads();
  if (tid < RB_)
    atomicAdd(&partial[(blockIdx.x & (PSLOTS - 1)) * RB_ + tid], red[tid]);
}

// ---- finalize + transpose: dead rows zero-filled without loading u ----
__global__ void fintrans_kernel(const float* __restrict__ u, const float* __restrict__ partial,
                                const int* __restrict__ rowptr, const int* __restrict__ cend,
                                const int* __restrict__ mask,
                                float* __restrict__ out)
{
  __shared__ float sinv[RB_];
  __shared__ float t[B_][72];
  int tid = threadIdx.x;   // 256
  if (tid < RB_){
    float s = 0.f;
    #pragma unroll 8
    for (int k = 0; k < PSLOTS; ++k) s += partial[k * RB_ + tid];
    sinv[tid] = frcp(fmaxf(1e-20f, s));
  }
  __syncthreads();
  int n0 = blockIdx.x * 64;
  for (int i = tid; i < 64 * B_; i += 256){
    int nl = i >> 5, b = i & 31;
    int n = n0 + nl;
    float v = 0.f;
    if (n < N_ && (mask[n] || cend[n] > rowptr[n])){
      size_t nb = (size_t)n * RB_;
      v = u[nb + b] * sinv[b] + u[nb + 32 + b] * sinv[32 + b] + u[nb + 64 + b] * sinv[64 + b];
    }
    t[b][nl] = v;
  }
  __syncthreads();
  for (int i = tid; i < 64 * B_; i += 256){
    int b = i >> 6, nl = i & 63;
    int n = n0 + nl;
    if (n < N_) out[(size_t)b * N_ + n] = t[b][nl];
  }
}

extern "C" void kernel_launch(void* const* d_in, const int* in_sizes, int n_in,
                              void* d_out, int out_size, void* d_ws, size_t ws_size,
                              hipStream_t stream)
{
  const int*   queries = (const int*)d_in[0];
  const int*   heads   = (const int*)d_in[1];
  const int*   rels    = (const int*)d_in[2];
  const int*   t_heads = (const int*)d_in[3];
  const int*   t_tails = (const int*)d_in[4];
  const int*   edeg    = (const int*)d_in[5];
  const float* qemb    = (const float*)d_in[6];
  const float* eemb    = (const float*)d_in[7];
  const float* qWih    = (const float*)d_in[8];
  const float* qWhh    = (const float*)d_in[9];
  const float* qbih    = (const float*)d_in[10];
  const float* qbhh    = (const float*)d_in[11];
  const float* eWih    = (const float*)d_in[12];
  const float* eWhh    = (const float*)d_in[13];
  const float* ebih    = (const float*)d_in[14];
  const float* ebhh    = (const float*)d_in[15];
  const float* qlinW   = (const float*)d_in[16];
  const float* qlinb   = (const float*)d_in[17];
  const float* elinW   = (const float*)d_in[18];
  const float* elinb   = (const float*)d_in[19];
  float* out = (float*)d_out;

  char* ws = (char*)d_ws;
  size_t off = 0;
  auto alloc = [&](size_t bytes){ void* p = ws + off; off += (bytes + 255) & ~(size_t)255; return p; };
  // bigB (19.2 MB): attn (4.8 MB) during [elstm, csr_fill]; then u3 (gather3 out).
  char*  bigB  = (char*)alloc((size_t)N_ * RB_ * 4);
  float* attn  = (float*)bigB;
  float* u3    = (float*)bigB;
  uint2* ents       = (uint2*)alloc((size_t)2 * E_ * 8);              // in-CSR (compact-filled)
  float* u2         = (float*)alloc((size_t)N_ * RB_ * 4);            // compact rows (worst-case N)
  uint2* ents2      = (uint2*)alloc((size_t)2 * E_ * 8);              // out-CSR (compact-filled)
  float* query_attn = (float*)alloc((size_t)R_ * T_ * B_ * (OPS_ + 1) * 4);
  u16*   wtile      = (u16*)  alloc((size_t)2 * 32 * 4 * 64 * 8 * 2);
  u16*   wonehot    = (u16*)  alloc((size_t)2 * 32 * 64 * 8 * 2);
  u16*   etile      = (u16*)  alloc((size_t)2 * 8 * 64 * 8 * 2);      // 16 KB
  int*   counts     = (int*)  alloc((size_t)(N_ + 1) * 4);            // [N_] = cidx counter
  int*   rowptr     = (int*)  alloc((size_t)(N_ + 1) * 4);
  int*   cursor     = (int*)  alloc((size_t)(N_ + 1) * 4);
  int*   cursor2    = (int*)  alloc((size_t)(N_ + 1) * 4);
  u8*    hs1        = (u8*)   alloc((size_t)N_);
  int*   mask       = (int*)  alloc((size_t)N_ * 4);
  int*   cidx       = (int*)  alloc((size_t)N_ * 4);
  float* sumsP      = (float*)alloc((size_t)PSLOTS * RB_ * 4);
  // total ~53 MB

  // counts + hs1 must be zero BEFORE front (csr_count atomics / bfs1 marks ride it);
  // u2 / mask / sumsP are zeroed inside front (consumed only later).
  hipMemsetAsync(counts, 0, (size_t)(N_ + 1) * 4, stream);
  hipMemsetAsync(hs1, 0, (size_t)N_, stream);

  front_kernel<<<WB_ + CB_ + BF_ + ZU_ + ZM_ + ZS_ + EB_, 512, 0, stream>>>(
      eWhh, eemb, eWih, ebih, ebhh, wtile, wonehot,
      t_heads, t_tails, counts, heads, hs1, u2, mask, sumsP, elinW, etile);
  // MEGA: [qattn 96][elstm 1563][scan + bfs2(+cidx claim) riders in the drain]
  elstm_kernel<<<QB_ + SCANBLK_ + 1 + BF2E_ + BF2N_, 512, 0, stream>>>(
      edeg, wtile, wonehot, etile, elinb, attn,
      counts, rowptr, cursor, cursor2,
      t_heads, t_tails, hs1, mask, cidx,
      queries, qemb, qWih, qWhh, qbih, qbhh, qlinW, qlinb, query_attn);
  // compact CSR fill (cursor/cursor2 become compact row ends)
  csr_fill_kernel<<<(E_ + 255) / 256, 256, 0, stream>>>(rels, t_heads, t_tails, attn,
                                                        mask, hs1, cursor, cursor2,
                                                        ents, ents2);
  // fused t=0 + t=1 sparse propagation into compact u2
  t01_kernel<<<RB_, 64, 0, stream>>>(heads, query_attn, rowptr, cursor2, ents2,
                                     cidx, u2);
  // t=2: dense gather over compact in-CSR, compact u2 source (attn dead; u3 = bigB)
  gather3_kernel<<<1024, 256, 0, stream>>>(u2, u3, query_attn, 2, rowptr, cursor,
                                           ents, mask, cidx, sumsP);
  fintrans_kernel<<<(N_ + 63) / 64, 256, 0, stream>>>(u3, sumsP, rowptr, cursor,
                                                      mask, out);
}

// Round 16
// 421.598 us; speedup vs baseline: 1.1471x; 1.1471x over previous
//
#include <hip/hip_runtime.h>

#define R_ 3
#define T_ 3
#define N_ 50000
#define OPS_ 24
#define E_ 400000
#define B_ 32
#define MAXDEG_ 8
#define QD_ 128
#define ED_ 128
#define H_ 128
#define G4_ (4*H_)   /* 512 */
#define HPAD 168     /* padded LDS h-row (bf16): 128 h + 25 one-hot + pad, 336 B */
#define PSLOTS 64    /* partial row-sum slots */
#define RB_ 96       /* 3 rounds x 32 batch */

/* front fat-kernel block ranges (512-thread blocks) */
#define WB_ ((2*32*5*64*8 + 511) / 512)        /* 320  wbuild */
#define CB_ ((E_ + 511) / 512)                 /* 782  csr_count */
#define BF_ ((E_ + 511) / 512)                 /* 782  bfs1 (1-hop mark) */
#define ZU_ 586                                /* u2 zero: 4.8M floats / 8192 */
#define ZM_ 25                                 /* mask zero: 12500 ints / 512 */
#define ZS_ 12                                 /* sumsP zero: 6144 / 512 */
#define EB_ 16                                 /* etile build: 8192 / 512 */

/* elstm mega-grid layout: [qattn 96][elstm 1563][scan 1][bfs2 880]
   Placement measured across r11-r14: qattn at HEAD costs ~5-10us slot pinning
   (mega 251-252); qattn at TAIL anchors the critical path (+27us, r13). Cheap
   1-2us scan/bfs2 riders at the tail are free (fit the drain's retire stagger).
   r15 lesson: cidx compaction of u2 REGRESSED (+59us) — the extra dependent
   cidx load on every edge's latency chain outweighed the working-set shrink,
   and contended CAS/counter atomics stalled the drain. Reverted. */
#define QB_ (R_ * B_)                          /* 96  qattn riders (first) */
#define SCANBLK_ ((N_ + 31) / 32)              /* 1563 elstm blocks */
#define BF2E_ ((E_ + 511) / 512)               /* 782 bfs2 edge riders */
#define BF2N_ ((N_ + 511) / 512)               /* 98  bfs2 node riders */

typedef unsigned short u16;
typedef unsigned char u8;
typedef __attribute__((ext_vector_type(8))) short bf16x8;     // 8 bf16 = 4 VGPRs
typedef __attribute__((ext_vector_type(8))) _Float16 f16x8;   // 8 f16  = 4 VGPRs
typedef __attribute__((ext_vector_type(4))) float f32x4;

#define BF16_ONE ((short)0x3F80)
#define LOG2E_  1.44269504f
#define LOG2E2_ 2.88539008f

__device__ __forceinline__ short f2bf(float f){
  union { float f; unsigned u; } v; v.f = f;
  unsigned r = v.u + 0x7fffu + ((v.u >> 16) & 1u);
  return (short)(r >> 16);
}
__device__ __forceinline__ float bf2f(u16 u){
  union { unsigned u; float f; } v; v.u = ((unsigned)u) << 16; return v.f;
}
__device__ __forceinline__ float frcp(float x){ return __builtin_amdgcn_rcpf(x); }
__device__ __forceinline__ float fsig(float x){ return frcp(1.0f + __expf(-x)); }
__device__ __forceinline__ float ftanh(float x){
  return __builtin_fmaf(2.0f, fsig(2.0f * x), -1.0f);
}
__device__ __forceinline__ float fexp2(float x){
#if __has_builtin(__builtin_amdgcn_exp2f)
  return __builtin_amdgcn_exp2f(x);
#else
  return __expf(x * 0.6931471806f);
#endif
}

// ------- query BiLSTM + attention: 512-thread body, dirs run concurrently -------
__device__ void qattn_body(int bid, const int* __restrict__ queries, const float* __restrict__ qemb,
    const float* __restrict__ qWih, const float* __restrict__ qWhh,
    const float* __restrict__ qbih, const float* __restrict__ qbhh,
    const float* __restrict__ qlinW, const float* __restrict__ qlinb,
    float* __restrict__ query_attn /* R,T,B,25 */)
{
  int r = bid / B_;
  int b = bid % B_;
  int tid = threadIdx.x;   // 512
  int d   = tid >> 8;      // direction
  int t2  = tid & 255;
  __shared__ float x[QD_];
  __shared__ float gx[2][G4_];
  __shared__ float h[2][H_], c[2][H_];
  __shared__ float gtmp[2][G4_];
  __shared__ float hh[2][T_][H_];
  __shared__ float lg[OPS_ + 1];

  int q = queries[b];
  if (tid < QD_) x[tid] = qemb[q * QD_ + tid];
  __syncthreads();

  const float* Wih = qWih + (size_t)(r * 2 + d) * G4_ * QD_;
  const float* Whh = qWhh + (size_t)(r * 2 + d) * G4_ * H_;
  const float* bih = qbih + (r * 2 + d) * G4_;
  const float* bhh = qbhh + (r * 2 + d) * G4_;
  for (int j = t2; j < G4_; j += 256){
    const float4* wr = (const float4*)(Wih + (size_t)j * QD_);
    float s = bih[j] + bhh[j];
    for (int k = 0; k < QD_ / 4; ++k){
      float4 wv = wr[k];
      s += wv.x * x[4*k] + wv.y * x[4*k+1] + wv.z * x[4*k+2] + wv.w * x[4*k+3];
    }
    gx[d][j] = s;
  }
  if (t2 < H_){ h[d][t2] = 0.f; c[d][t2] = 0.f; }
  __syncthreads();
  for (int t = 0; t < T_; ++t){
    for (int j = t2; j < G4_; j += 256){
      const float4* wr = (const float4*)(Whh + (size_t)j * H_);
      float s = 0.f;
      for (int k = 0; k < H_ / 4; ++k){
        float4 wv = wr[k];
        s += wv.x * h[d][4*k] + wv.y * h[d][4*k+1] + wv.z * h[d][4*k+2] + wv.w * h[d][4*k+3];
      }
      gtmp[d][j] = gx[d][j] + s;
    }
    __syncthreads();
    if (t2 < H_){
      float gi = gtmp[d][t2], gf = gtmp[d][t2 + H_], gg = gtmp[d][t2 + 2*H_], go = gtmp[d][t2 + 3*H_];
      float cn = fsig(gf) * c[d][t2] + fsig(gi) * ftanh(gg);
      float hn = fsig(go) * ftanh(cn);
      c[d][t2] = cn; h[d][t2] = hn;
      hh[d][t][t2] = hn;
    }
    __syncthreads();
  }

  for (int t = 0; t < T_; ++t){
    if (tid < OPS_ + 1){
      const float* wr = qlinW + tid * (2 * H_);
      float s = qlinb[tid];
      for (int k = 0; k < H_; ++k) s += wr[k] * hh[0][t][k];
      for (int k = 0; k < H_; ++k) s += wr[H_ + k] * hh[1][T_ - 1 - t][k];
      lg[tid] = s;
    }
    __syncthreads();
    if (tid == 0){
      float m = -1e30f;
      for (int o = 0; o < OPS_ + 1; ++o) m = fmaxf(m, lg[o]);
      float sum = 0.f;
      for (int o = 0; o < OPS_ + 1; ++o){ float e = __expf(lg[o] - m); lg[o] = e; sum += e; }
      float inv = frcp(sum);
      for (int o = 0; o < OPS_ + 1; ++o) lg[o] *= inv;
    }
    __syncthreads();
    if (tid < OPS_ + 1) query_attn[((size_t)(r * T_ + t) * B_ + b) * (OPS_ + 1) + tid] = lg[tid];
    __syncthreads();
  }
}

// ---- build B-operand buffers in MFMA-fragment order (eproj folded in) ----
__device__ void wbuild_body(int bid, const float* __restrict__ eWhh,
                            const float* __restrict__ eemb, const float* __restrict__ eWih,
                            const float* __restrict__ ebih, const float* __restrict__ ebhh,
                            u16* __restrict__ wtile, u16* __restrict__ wonehot)
{
  int idx = bid * 512 + threadIdx.x;    // 2*32*5*64*8 = 163840
  if (idx >= 2 * 32 * 5 * 64 * 8) return;
  int jj = idx & 7;
  int lane = (idx >> 3) & 63;
  int kc = (idx >> 9) % 5;
  int gtile = (idx / (8 * 64 * 5)) & 31;
  int dir = idx / (8 * 64 * 5 * 32);
  int row = lane >> 4, col = lane & 15;
  int j = gtile * 16 + col;
  float sc = ((gtile >> 3) == 2) ? LOG2E2_ : LOG2E_;   // gate g rows get 2*log2e
  if (kc < 4){
    int k = kc * 32 + row * 8 + jj;
    float v = eWhh[((size_t)dir * G4_ + j) * H_ + k] * sc;
    wtile[((((size_t)dir * 32 + gtile) * 4 + kc) * 64 + lane) * 8 + jj] = (u16)f2bf(v);
  } else {
    int vdeg = row * 8 + jj;   // 0..31
    float v = 0.f;
    if (vdeg <= OPS_){
      const float4* wr = (const float4*)(eWih + (size_t)(dir * G4_ + j) * ED_);
      const float4* er = (const float4*)(eemb + (size_t)vdeg * ED_);
      float s = ebih[dir * G4_ + j] + ebhh[dir * G4_ + j];
      for (int k = 0; k < ED_ / 4; ++k){
        float4 wv = wr[k], ev = er[k];
        s += wv.x * ev.x + wv.y * ev.y + wv.z * ev.z + wv.w * ev.w;
      }
      v = s * sc;
    }
    wonehot[(((size_t)dir * 32 + gtile) * 64 + lane) * 8 + jj] = (u16)f2bf(v);
  }
}

__device__ void csr_count_body(int bid, const int* __restrict__ theads,
                               const int* __restrict__ ttails, int* __restrict__ counts)
{
  int e = bid * 512 + threadIdx.x;
  if (e < E_){
    atomicAdd(&counts[ttails[e]], 1);
    atomicAdd(&counts[theads[e]], 1);
  }
}

// ---- bfs1: mark 1-hop neighborhood of heads (both edge roles) + heads selves.
__device__ void bfs1_body(int bid, const int* __restrict__ heads,
                          const int* __restrict__ theads, const int* __restrict__ ttails,
                          u8* __restrict__ hs1)
{
  if (bid == 0 && threadIdx.x < B_) hs1[heads[threadIdx.x]] = 1;
  int e = bid * 512 + threadIdx.x;
  if (e < E_){
    int a = theads[e], t = ttails[e];
    #pragma unroll 8
    for (int i = 0; i < B_; ++i){
      int hd = heads[i];             // uniform -> scalar loads
      if (a == hd) hs1[t] = 1;
      if (t == hd) hs1[a] = 1;
    }
  }
}

// ---- front fat-kernel: wbuild | csr_count | bfs1 | zero(u2,mask,sumsP) | etile
__global__ __launch_bounds__(512) void front_kernel(
    const float* eWhh, const float* eemb, const float* eWih,
    const float* ebih, const float* ebhh, u16* wtile, u16* wonehot,
    const int* theads, const int* ttails, int* counts,
    const int* heads, u8* hs1,
    float* u2, int* maski, float* sumsP,
    const float* elinW, u16* etile)
{
  int bid = blockIdx.x;
  int tid = threadIdx.x;
  if (bid < WB_){
    wbuild_body(bid, eWhh, eemb, eWih, ebih, ebhh, wtile, wonehot);
  } else if (bid < WB_ + CB_){
    csr_count_body(bid - WB_, theads, ttails, counts);
  } else if (bid < WB_ + CB_ + BF_){
    bfs1_body(bid - WB_ - CB_, heads, theads, ttails, hs1);
  } else if (bid < WB_ + CB_ + BF_ + ZU_){
    int zb = bid - WB_ - CB_ - BF_;
    float4 z = {0.f, 0.f, 0.f, 0.f};
    size_t base = (size_t)zb * 8192 + tid * 4;
    #pragma unroll
    for (int k = 0; k < 4; ++k){
      size_t idx = base + (size_t)k * 2048;
      if (idx < (size_t)N_ * RB_) *(float4*)&u2[idx] = z;
    }
  } else if (bid < WB_ + CB_ + BF_ + ZU_ + ZM_){
    int mi = (bid - WB_ - CB_ - BF_ - ZU_) * 512 + tid;
    if (mi < (N_ + 3) / 4) maski[mi] = 0;
  } else if (bid < WB_ + CB_ + BF_ + ZU_ + ZM_ + ZS_){
    int si = (bid - WB_ - CB_ - BF_ - ZU_ - ZM_) * 512 + tid;
    if (si < PSLOTS * RB_) sumsP[si] = 0.f;
  } else {
    // elinW -> f16 MFMA B-frags: [2 op-tiles][8 ksteps][64 lanes][8] (16 KB)
    int idx = (bid - (WB_ + CB_ + BF_ + ZU_ + ZM_ + ZS_)) * 512 + tid;   // 0..8191
    if (idx < 8192){
      int jj = idx & 7;
      int lane = (idx >> 3) & 63;
      int ks = (idx >> 9) & 7;
      int ot = idx >> 12;
      int op = ot * 16 + (lane & 15);
      int k  = ks * 32 + (lane >> 4) * 8 + jj;
      float v = (op < OPS_) ? elinW[(size_t)op * (2 * H_) + k] : 0.f;
      _Float16 hv = (_Float16)v;
      etile[idx] = *(const u16*)&hv;
    }
  }
}

// ---- bfs2 body: 2-hop closure. mask = hs1 U adj(hs1). Superset of u2's rows.
__device__ void bfs2_body(int bid, const int* __restrict__ theads,
                          const int* __restrict__ ttails,
                          const u8* __restrict__ hs1, u8* __restrict__ mask)
{
  if (bid < BF2E_){
    int e = bid * 512 + threadIdx.x;
    if (e < E_){
      int a = theads[e], t = ttails[e];
      if (hs1[a]) mask[t] = 1;
      if (hs1[t]) mask[a] = 1;
    }
  } else {
    int n = (bid - BF2E_) * 512 + threadIdx.x;
    if (n < N_ && hs1[n]) mask[n] = 1;
  }
}

// ---- coalesced tile scan (512 threads, tail rider of the elstm grid).
__device__ void scan_body(const int* __restrict__ counts, int* __restrict__ rowptr,
                          int* __restrict__ cursor, int* __restrict__ cursor2)
{
  __shared__ int wsum[8];
  int t = threadIdx.x;
  int lane = t & 63, wv = t >> 6;
  int carry = 0;   // live only in thread 0
  for (int base = 0; base < N_; base += 2048){
    int idx = base + t * 4;
    int c0 = 0, c1 = 0, c2 = 0, c3 = 0;
    if (idx + 3 < N_){
      int4 c = *(const int4*)&counts[idx];
      c0 = c.x; c1 = c.y; c2 = c.z; c3 = c.w;
    } else {
      if (idx     < N_) c0 = counts[idx];
      if (idx + 1 < N_) c1 = counts[idx + 1];
      if (idx + 2 < N_) c2 = counts[idx + 2];
      if (idx + 3 < N_) c3 = counts[idx + 3];
    }
    int s = c0 + c1 + c2 + c3;
    int sc = s;                          // inclusive wave scan
    #pragma unroll
    for (int off = 1; off < 64; off <<= 1){
      int v = __shfl_up(sc, off);
      if (lane >= off) sc += v;
    }
    if (lane == 63) wsum[wv] = sc;
    __syncthreads();
    if (t == 0){
      int acc = carry;
      #pragma unroll
      for (int w = 0; w < 8; ++w){ int v = wsum[w]; wsum[w] = acc; acc += v; }
      carry = acc;
    }
    __syncthreads();
    int excl = wsum[wv] + (sc - s);
    int r0 = excl, r1 = r0 + c0, r2 = r1 + c1, r3 = r2 + c2;
    if (idx + 3 < N_){
      int4 rv; rv.x = r0; rv.y = r1; rv.z = r2; rv.w = r3;
      *(int4*)&rowptr[idx]  = rv;
      *(int4*)&cursor[idx]  = rv;
      *(int4*)&cursor2[idx] = rv;
    } else {
      if (idx     < N_){ rowptr[idx]   = r0; cursor[idx]   = r0; cursor2[idx]   = r0; }
      if (idx + 1 < N_){ rowptr[idx+1] = r1; cursor[idx+1] = r1; cursor2[idx+1] = r1; }
      if (idx + 2 < N_){ rowptr[idx+2] = r2; cursor[idx+2] = r2; cursor2[idx+2] = r2; }
      if (idx + 3 < N_){ rowptr[idx+3] = r3; cursor[idx+3] = r3; cursor2[idx+3] = r3; }
    }
  }
  if (t == 0) rowptr[N_] = carry;
}

// ------ elstm MEGA-kernel, grid = [qattn 96][elstm 1563][scan+bfs2 881] (r12 order).
__global__ __launch_bounds__(512, 4) void elstm_kernel(
    const int* __restrict__ degs,
    const u16* __restrict__ wtile, const u16* __restrict__ wonehot,
    const u16* __restrict__ etile, const float* __restrict__ elinb,
    float* __restrict__ attn /* N,24 */,
    const int* __restrict__ counts, int* __restrict__ rowptr,
    int* __restrict__ cursor, int* __restrict__ cursor2,
    const int* __restrict__ theads, const int* __restrict__ ttails,
    const u8* __restrict__ hs1, u8* __restrict__ mask,
    const int* __restrict__ queries, const float* __restrict__ qemb,
    const float* __restrict__ qWih, const float* __restrict__ qWhh,
    const float* __restrict__ qbih, const float* __restrict__ qbhh,
    const float* __restrict__ qlinW, const float* __restrict__ qlinb,
    float* __restrict__ query_attn)
{
  int bid = blockIdx.x;
  if (bid < QB_){
    qattn_body(bid, queries, qemb, qWih, qWhh, qbih, qbhh, qlinW, qlinb, query_attn);
    return;
  }
  int eb = bid - QB_;
  if (eb >= SCANBLK_){
    int rid = eb - SCANBLK_;
    if (rid == 0) scan_body(counts, rowptr, cursor, cursor2);
    else          bfs2_body(rid - 1, theads, ttails, hs1, mask);
    return;
  }

  int tid = threadIdx.x;
  int lane = tid & 63;
  int w = tid >> 6;          // wave 0..7
  int wu = __builtin_amdgcn_readfirstlane(w);   // provably wave-uniform
  int row = lane >> 4, col = lane & 15;
  int ebase = eb * 32;

  __shared__ __align__(16) short hl[2][32 * HPAD];   // 2 x 10.5 KB ping-pong
  __shared__ __align__(16) short hfin[32 * 136];     // dir0 final h (8.5 KB)
  __shared__ float lgs[32][33];                      // epilogue logits (4.2 KB)

  int eg0 = ebase + tid; if (eg0 >= N_) eg0 = N_ - 1;   // valid for tid<32 use

  for (int i = tid; i < 2 * 32 * HPAD; i += 512) ((short*)hl)[i] = 0;
  __syncthreads();
  if (tid < 32) hl[0][tid * HPAD + H_ + degs[(size_t)eg0 * MAXDEG_ + 0]] = BF16_ONE;
  __syncthreads();

  int swzr = (col >> 2) & 3;   // read-side swizzle for entities col and 16+col

  for (int dir = 0; dir < 2; ++dir){
    const u16* Wt  = wtile   + (size_t)dir * 32 * 4 * 64 * 8;
    const u16* Woh = wonehot + (size_t)dir * 32 * 64 * 8;
    const u16* W0 = Wt + (size_t)((0 * 8 + wu) * 4 * 64) * 8;
    const u16* W1 = Wt + (size_t)((1 * 8 + wu) * 4 * 64) * 8;
    const u16* W2 = Wt + (size_t)((2 * 8 + wu) * 4 * 64) * 8;
    const u16* W3 = Wt + (size_t)((3 * 8 + wu) * 4 * 64) * 8;
    const u16* O0 = Woh + (size_t)((0 * 8 + wu) * 64) * 8;
    const u16* O1 = Woh + (size_t)((1 * 8 + wu) * 64) * 8;
    const u16* O2 = Woh + (size_t)((2 * 8 + wu) * 64) * 8;
    const u16* O3 = Woh + (size_t)((3 * 8 + wu) * 64) * 8;
    float cst[8];
    #pragma unroll
    for (int i = 0; i < 8; ++i) cst[i] = 0.f;

    for (int t = 0; t < MAXDEG_; ++t){
      const short* hb = hl[t & 1];          // holds h_t (+ one-hot for step t)
      short*       hw = hl[(t + 1) & 1];    // receives h_{t+1}
      f32x4 acc[8];
      #pragma unroll
      for (int i = 0; i < 8; ++i) acc[i] = (f32x4){0.f, 0.f, 0.f, 0.f};

      #pragma unroll 2
      for (int kc = 0; kc < 4; ++kc){
        bf16x8 af0 = *(const bf16x8*)&hb[(col) * HPAD + kc * 32 + (row ^ swzr) * 8];
        bf16x8 af1 = *(const bf16x8*)&hb[(16 + col) * HPAD + kc * 32 + (row ^ swzr) * 8];
        int lo = (kc * 64 + lane) * 8;
        bf16x8 b0 = *(const bf16x8*)(W0 + lo);
        bf16x8 b1 = *(const bf16x8*)(W1 + lo);
        bf16x8 b2 = *(const bf16x8*)(W2 + lo);
        bf16x8 b3 = *(const bf16x8*)(W3 + lo);
        acc[0] = __builtin_amdgcn_mfma_f32_16x16x32_bf16(af0, b0, acc[0], 0, 0, 0);
        acc[1] = __builtin_amdgcn_mfma_f32_16x16x32_bf16(af1, b0, acc[1], 0, 0, 0);
        acc[2] = __builtin_amdgcn_mfma_f32_16x16x32_bf16(af0, b1, acc[2], 0, 0, 0);
        acc[3] = __builtin_amdgcn_mfma_f32_16x16x32_bf16(af1, b1, acc[3], 0, 0, 0);
        acc[4] = __builtin_amdgcn_mfma_f32_16x16x32_bf16(af0, b2, acc[4], 0, 0, 0);
        acc[5] = __builtin_amdgcn_mfma_f32_16x16x32_bf16(af1, b2, acc[5], 0, 0, 0);
        acc[6] = __builtin_amdgcn_mfma_f32_16x16x32_bf16(af0, b3, acc[6], 0, 0, 0);
        acc[7] = __builtin_amdgcn_mfma_f32_16x16x32_bf16(af1, b3, acc[7], 0, 0, 0);
      }
      {
        bf16x8 af0 = *(const bf16x8*)&hb[(col) * HPAD + H_ + row * 8];
        bf16x8 af1 = *(const bf16x8*)&hb[(16 + col) * HPAD + H_ + row * 8];
        int lo = lane * 8;
        bf16x8 b0 = *(const bf16x8*)(O0 + lo);
        bf16x8 b1 = *(const bf16x8*)(O1 + lo);
        bf16x8 b2 = *(const bf16x8*)(O2 + lo);
        bf16x8 b3 = *(const bf16x8*)(O3 + lo);
        acc[0] = __builtin_amdgcn_mfma_f32_16x16x32_bf16(af0, b0, acc[0], 0, 0, 0);
        acc[1] = __builtin_amdgcn_mfma_f32_16x16x32_bf16(af1, b0, acc[1], 0, 0, 0);
        acc[2] = __builtin_amdgcn_mfma_f32_16x16x32_bf16(af0, b1, acc[2], 0, 0, 0);
        acc[3] = __builtin_amdgcn_mfma_f32_16x16x32_bf16(af1, b1, acc[3], 0, 0, 0);
        acc[4] = __builtin_amdgcn_mfma_f32_16x16x32_bf16(af0, b2, acc[4], 0, 0, 0);
        acc[5] = __builtin_amdgcn_mfma_f32_16x16x32_bf16(af1, b2, acc[5], 0, 0, 0);
        acc[6] = __builtin_amdgcn_mfma_f32_16x16x32_bf16(af0, b3, acc[6], 0, 0, 0);
        acc[7] = __builtin_amdgcn_mfma_f32_16x16x32_bf16(af1, b3, acc[7], 0, 0, 0);
      }

      #pragma unroll
      for (int mt = 0; mt < 2; ++mt){
        #pragma unroll
        for (int reg = 0; reg < 4; ++reg){
          int e = mt * 16 + row * 4 + reg;
          int jsw = (((wu * 2 + (col >> 3)) ^ row) * 8) + (col & 7);
          float Gi = acc[0 + mt][reg];
          float Gf = acc[2 + mt][reg];
          float Gg = acc[4 + mt][reg];
          float Go = acc[6 + mt][reg];
          int ci = mt * 4 + reg;
          float ea = fexp2(-Gi);
          float ef = fexp2(-Gf);
          float eb2 = fexp2(-Gg);
          float eo = fexp2(-Go);
          float t1 = 1.f + ef, t2 = 1.f + ea, t3 = 1.f + eb2;
          float p = t2 * t3;
          float num = __builtin_fmaf(cst[ci], p, (1.f - eb2) * t1);
          float cn = num * frcp(t1 * p);
          float ed = fexp2(cn * (-LOG2E2_));
          float hn = (1.f - ed) * frcp((1.f + eo) * (1.f + ed));
          cst[ci] = cn;
          hw[e * HPAD + jsw] = f2bf(hn);
        }
      }
      if (tid < 32){
        const int* dr = degs + (size_t)eg0 * MAXDEG_;
        if (t >= 1)
          hw[tid * HPAD + H_ + dr[dir ? (MAXDEG_ - t) : (t - 1)]] = 0;
        if (t < MAXDEG_ - 1)
          hw[tid * HPAD + H_ + dr[dir ? (MAXDEG_ - 2 - t) : (t + 1)]] = BF16_ONE;
      }
      __syncthreads();
    }

    if (dir == 0){
      for (int i = tid; i < 32 * 16; i += 512){
        int e = i >> 4, c = i & 15;
        int sz = (e >> 2) & 3;
        *(bf16x8*)&hfin[e * 136 + c * 8] =
            *(const bf16x8*)&hl[0][e * HPAD + ((c ^ sz) * 8)];
      }
      __syncthreads();
      for (int i = tid; i < 2 * 32 * HPAD; i += 512) ((short*)hl)[i] = 0;
      __syncthreads();
      if (tid < 32) hl[0][tid * HPAD + H_ + degs[(size_t)eg0 * MAXDEG_ + (MAXDEG_ - 1)]] = BF16_ONE;
      __syncthreads();
    }
  }

  // fused entity-attention epilogue
  if (wu < 4){
    int mt = wu >> 1, ot = wu & 1;
    int e2 = mt * 16 + col;
    f32x4 accL = (f32x4){0.f, 0.f, 0.f, 0.f};
    #pragma unroll
    for (int ks = 0; ks < 8; ++ks){
      bf16x8 ra;
      if (ks < 4) ra = *(const bf16x8*)&hfin[e2 * 136 + ks * 32 + row * 8];
      else        ra = *(const bf16x8*)&hl[0][e2 * HPAD + (ks - 4) * 32 + (row ^ swzr) * 8];
      f16x8 af;
      #pragma unroll
      for (int jj = 0; jj < 8; ++jj) af[jj] = (_Float16)bf2f((u16)ra[jj]);
      f16x8 bfr = *(const f16x8*)(etile + (((size_t)(ot * 8 + ks)) * 64 + lane) * 8);
      accL = __builtin_amdgcn_mfma_f32_16x16x32_f16(af, bfr, accL, 0, 0, 0);
    }
    #pragma unroll
    for (int reg = 0; reg < 4; ++reg){
      int ent = mt * 16 + (lane >> 4) * 4 + reg;
      int op  = ot * 16 + (lane & 15);
      float bb = (op < OPS_) ? elinb[op] : 0.f;
      lgs[ent][op] = accL[reg] + bb;
    }
  }
  __syncthreads();
  if (tid < 32){
    int n = ebase + tid;
    if (n < N_){
      float m = -1e30f;
      #pragma unroll
      for (int o = 0; o < OPS_; ++o) m = fmaxf(m, lgs[tid][o]);
      float s = 0.f;
      #pragma unroll
      for (int o = 0; o < OPS_; ++o) s += __expf(lgs[tid][o] - m);
      float inv = frcp(s);
      #pragma unroll
      for (int o = 0; o < OPS_; ++o)
        attn[(size_t)n * OPS_ + o] = __expf(lgs[tid][o] - m) * inv;
    }
  }
}

// ---- compact CSR fill (r10-exact) ----
__global__ void csr_fill_kernel(const int* __restrict__ rels, const int* __restrict__ theads,
                                const int* __restrict__ ttails, const float* __restrict__ attn,
                                const u8* __restrict__ mask, const u8* __restrict__ hs1,
                                int* __restrict__ cursor, int* __restrict__ cursor2,
                                uint2* __restrict__ ents, uint2* __restrict__ ents2)
{
  int e = blockIdx.x * 256 + threadIdx.x;
  if (e < E_){
    int hh = theads[e], tt = ttails[e];
    int mh = mask[hh], mt = mask[tt];
    if (!(mh | mt)) return;
    int rel = rels[e];
    unsigned wb = __float_as_uint(attn[(size_t)hh * OPS_ + rel]);
    if (mh){                         // fwd: src hh -> row tt
      uint2 v1; v1.x = (unsigned)hh | ((unsigned)rel << 16); v1.y = wb;
      ents[atomicAdd(&cursor[tt], 1)] = v1;
    }
    if (mt){                         // rev: src tt -> row hh
      uint2 v2; v2.x = (unsigned)tt | ((unsigned)(rel + OPS_/2) << 16); v2.y = wb;
      ents[atomicAdd(&cursor[hh], 1)] = v2;
    }
    if (hs1[hh]){                    // out-edge of hh
      uint2 w1; w1.x = (unsigned)tt | ((unsigned)rel << 16); w1.y = wb;
      ents2[atomicAdd(&cursor2[hh], 1)] = w1;
    }
    if (hs1[tt]){                    // out-edge of tt (reverse op)
      uint2 w2; w2.x = (unsigned)hh | ((unsigned)(rel + OPS_/2) << 16); w2.y = wb;
      ents2[atomicAdd(&cursor2[tt], 1)] = w2;
    }
  }
}

// ---- fused sparse t=0 + t=1 (r10-exact) ----
__global__ void t01_kernel(const int* __restrict__ heads, const float* __restrict__ query_attn,
                           const int* __restrict__ rowptr, const int* __restrict__ cend2,
                           const uint2* __restrict__ ents2, float* __restrict__ u2)
{
  __shared__ float qa0[OPS_ + 1], qa1[OPS_ + 1];
  int blk = blockIdx.x;   // 0..95
  int r = blk >> 5, b = blk & 31;
  int rb = r * 32 + b;
  int tid = threadIdx.x;  // 64
  if (tid < OPS_ + 1){
    qa0[tid] = query_attn[((size_t)(r * T_ + 0) * B_ + b) * (OPS_ + 1) + tid];
    qa1[tid] = query_attn[((size_t)(r * T_ + 1) * B_ + b) * (OPS_ + 1) + tid];
  }
  __syncthreads();
  int hd = heads[b];
  int beg = rowptr[hd], end = cend2[hd];
  float q024 = qa0[OPS_], q124 = qa1[OPS_];
  if (tid == 0) atomicAdd(&u2[(size_t)hd * RB_ + rb], q124 * q024);
  for (int i = beg + tid; i < end; i += 64){
    uint2 e1 = ents2[i];
    int s  = (int)(e1.x & 0xFFFFu);
    int r1 = (int)(e1.x >> 16);
    float w1 = __uint_as_float(e1.y);
    atomicAdd(&u2[(size_t)s * RB_ + rb], w1 * (q124 * qa0[r1] + qa1[r1] * q024));
    float v1 = qa0[r1] * w1;      // this path's share of u1[s]
    int b2 = rowptr[s], e2e = cend2[s];
    for (int jj = b2; jj < e2e; ++jj){
      uint2 e2 = ents2[jj];
      int d2 = (int)(e2.x & 0xFFFFu);
      int r2 = (int)(e2.x >> 16);
      atomicAdd(&u2[(size_t)d2 * RB_ + rb], qa1[r2] * __uint_as_float(e2.y) * v1);
    }
  }
}

// ---- dense gather (t=2): half-wave per node, grid-stride, one qas stage/block ----
__global__ __launch_bounds__(256) void gather3_kernel(
    const float* __restrict__ ucur, float* __restrict__ unxt,
    const float* __restrict__ query_attn, int t,
    const int* __restrict__ rowptr, const int* __restrict__ cend,
    const uint2* __restrict__ ents, const u8* __restrict__ mask,
    float* __restrict__ partial /* PSLOTS x 96 */)
{
  __shared__ float qas[3 * B_ * (OPS_ + 1)];  // [r][b][o]
  __shared__ float red[RB_];
  int tid = threadIdx.x;
  for (int i = tid; i < 3 * B_ * (OPS_ + 1); i += 256){
    int r = i / (B_ * (OPS_ + 1));
    int rem = i - r * (B_ * (OPS_ + 1));
    qas[i] = query_attn[(size_t)(r * T_ + t) * B_ * (OPS_ + 1) + rem];
  }
  if (tid < RB_) red[tid] = 0.f;
  __syncthreads();
  int b   = tid & 31;
  int hw2 = tid >> 5;                  // half-wave 0..7, one node each
  const float* q0 = &qas[0 * 800 + b * (OPS_ + 1)];
  const float* q1 = &qas[1 * 800 + b * (OPS_ + 1)];
  const float* q2 = &qas[2 * 800 + b * (OPS_ + 1)];
  float s0a = 0.f, s1a = 0.f, s2a = 0.f;
  for (int n = blockIdx.x * 8 + hw2; n < N_; n += gridDim.x * 8){
    int beg = rowptr[n], end = cend[n];
    int mk = mask[n];
    if (end == beg && !mk) continue;   // dead row: fintrans zero-fills
    size_t nb = (size_t)n * RB_;
    float a0 = 0.f, a1 = 0.f, a2 = 0.f;
    if (mk){
      a0 = ucur[nb + b]      * q0[OPS_];
      a1 = ucur[nb + 32 + b] * q1[OPS_];
      a2 = ucur[nb + 64 + b] * q2[OPS_];
    }
    #pragma unroll 2
    for (int i = beg; i < end; ++i){
      uint2 e0 = ents[i];              // uniform across the half -> broadcast
      size_t s0 = (size_t)(e0.x & 0xFFFFu) * RB_;
      int r0 = (int)(e0.x >> 16);
      float w0 = __uint_as_float(e0.y);
      a0 += q0[r0] * w0 * ucur[s0 + b];
      a1 += q1[r0] * w0 * ucur[s0 + 32 + b];
      a2 += q2[r0] * w0 * ucur[s0 + 64 + b];
    }
    unxt[nb + b]      = a0;
    unxt[nb + 32 + b] = a1;
    unxt[nb + 64 + b] = a2;
    s0a += a0; s1a += a1; s2a += a2;
  }
  atomicAdd(&red[b], s0a);
  atomicAdd(&red[32 + b], s1a);
  atomicAdd(&red[64 + b], s2a);
  __syncthreads();
  if (tid < RB_)
    atomicAdd(&partial[(blockIdx.x & (PSLOTS - 1)) * RB_ + tid], red[tid]);
}

// ---- finalize + transpose: dead rows zero-filled without loading u ----
__global__ void fintrans_kernel(const float* __restrict__ u, const float* __restrict__ partial,
                                const int* __restrict__ rowptr, const int* __restrict__ cend,
                                const u8* __restrict__ mask,
                                float* __restrict__ out)
{
  __shared__ float sinv[RB_];
  __shared__ float t[B_][72];
  int tid = threadIdx.x;   // 256
  if (tid < RB_){
    float s = 0.f;
    #pragma unroll 8
    for (int k = 0; k < PSLOTS; ++k) s += partial[k * RB_ + tid];
    sinv[tid] = frcp(fmaxf(1e-20f, s));
  }
  __syncthreads();
  int n0 = blockIdx.x * 64;
  for (int i = tid; i < 64 * B_; i += 256){
    int nl = i >> 5, b = i & 31;
    int n = n0 + nl;
    float v = 0.f;
    if (n < N_ && (mask[n] || cend[n] > rowptr[n])){
      size_t nb = (size_t)n * RB_;
      v = u[nb + b] * sinv[b] + u[nb + 32 + b] * sinv[32 + b] + u[nb + 64 + b] * sinv[64 + b];
    }
    t[b][nl] = v;
  }
  __syncthreads();
  for (int i = tid; i < 64 * B_; i += 256){
    int b = i >> 6, nl = i & 63;
    int n = n0 + nl;
    if (n < N_) out[(size_t)b * N_ + n] = t[b][nl];
  }
}

extern "C" void kernel_launch(void* const* d_in, const int* in_sizes, int n_in,
                              void* d_out, int out_size, void* d_ws, size_t ws_size,
                              hipStream_t stream)
{
  const int*   queries = (const int*)d_in[0];
  const int*   heads   = (const int*)d_in[1];
  const int*   rels    = (const int*)d_in[2];
  const int*   t_heads = (const int*)d_in[3];
  const int*   t_tails = (const int*)d_in[4];
  const int*   edeg    = (const int*)d_in[5];
  const float* qemb    = (const float*)d_in[6];
  const float* eemb    = (const float*)d_in[7];
  const float* qWih    = (const float*)d_in[8];
  const float* qWhh    = (const float*)d_in[9];
  const float* qbih    = (const float*)d_in[10];
  const float* qbhh    = (const float*)d_in[11];
  const float* eWih    = (const float*)d_in[12];
  const float* eWhh    = (const float*)d_in[13];
  const float* ebih    = (const float*)d_in[14];
  const float* ebhh    = (const float*)d_in[15];
  const float* qlinW   = (const float*)d_in[16];
  const float* qlinb   = (const float*)d_in[17];
  const float* elinW   = (const float*)d_in[18];
  const float* elinb   = (const float*)d_in[19];
  float* out = (float*)d_out;

  char* ws = (char*)d_ws;
  size_t off = 0;
  auto alloc = [&](size_t bytes){ void* p = ws + off; off += (bytes + 255) & ~(size_t)255; return p; };
  // bigB (19.2 MB): attn (4.8 MB) during [elstm, csr_fill]; then u3 (gather3 out).
  char*  bigB  = (char*)alloc((size_t)N_ * RB_ * 4);
  float* attn  = (float*)bigB;
  float* u3    = (float*)bigB;
  uint2* ents       = (uint2*)alloc((size_t)2 * E_ * 8);              // in-CSR (compact-filled)
  float* u2         = (float*)alloc((size_t)N_ * RB_ * 4);            // 19.2 MB
  uint2* ents2      = (uint2*)alloc((size_t)2 * E_ * 8);              // out-CSR (compact-filled)
  float* query_attn = (float*)alloc((size_t)R_ * T_ * B_ * (OPS_ + 1) * 4);
  u16*   wtile      = (u16*)  alloc((size_t)2 * 32 * 4 * 64 * 8 * 2);
  u16*   wonehot    = (u16*)  alloc((size_t)2 * 32 * 64 * 8 * 2);
  u16*   etile      = (u16*)  alloc((size_t)2 * 8 * 64 * 8 * 2);      // 16 KB
  int*   counts     = (int*)  alloc((size_t)(N_ + 1) * 4);
  int*   rowptr     = (int*)  alloc((size_t)(N_ + 1) * 4);
  int*   cursor     = (int*)  alloc((size_t)(N_ + 1) * 4);
  int*   cursor2    = (int*)  alloc((size_t)(N_ + 1) * 4);
  u8*    hs1        = (u8*)   alloc((size_t)N_);
  u8*    mask       = (u8*)   alloc((size_t)N_);
  float* sumsP      = (float*)alloc((size_t)PSLOTS * RB_ * 4);
  // total ~52 MB

  // counts + hs1 must be zero BEFORE front (csr_count atomics / bfs1 marks ride it);
  // u2 / mask / sumsP are zeroed inside front (consumed only later).
  hipMemsetAsync(counts, 0, (size_t)(N_ + 1) * 4, stream);
  hipMemsetAsync(hs1, 0, (size_t)N_, stream);

  front_kernel<<<WB_ + CB_ + BF_ + ZU_ + ZM_ + ZS_ + EB_, 512, 0, stream>>>(
      eWhh, eemb, eWih, ebih, ebhh, wtile, wonehot,
      t_heads, t_tails, counts, heads, hs1, u2, (int*)mask, sumsP, elinW, etile);
  // MEGA: [qattn 96][elstm 1563][scan + bfs2 riders — backfill the drain]
  elstm_kernel<<<QB_ + SCANBLK_ + 1 + BF2E_ + BF2N_, 512, 0, stream>>>(
      edeg, wtile, wonehot, etile, elinb, attn,
      counts, rowptr, cursor, cursor2,
      t_heads, t_tails, hs1, mask,
      queries, qemb, qWih, qWhh, qbih, qbhh, qlinW, qlinb, query_attn);
  // compact CSR fill (cursor/cursor2 become compact row ends)
  csr_fill_kernel<<<(E_ + 255) / 256, 256, 0, stream>>>(rels, t_heads, t_tails, attn,
                                                        mask, hs1, cursor, cursor2,
                                                        ents, ents2);
  // fused t=0 + t=1 sparse propagation into u2
  t01_kernel<<<RB_, 64, 0, stream>>>(heads, query_attn, rowptr, cursor2, ents2, u2);
  // t=2: dense gather over compact in-CSR (attn dead; u3 overwrites bigB)
  gather3_kernel<<<1024, 256, 0, stream>>>(u2, u3, query_attn, 2, rowptr, cursor,
                                           ents, mask, sumsP);
  fintrans_kernel<<<(N_ + 63) / 64, 256, 0, stream>>>(u3, sumsP, rowptr, cursor,
                                                      mask, out);
}